// Round 3
// baseline (6984.007 us; speedup 1.0000x reference)
//
#include <hip/hip_runtime.h>
#include <cstdint>
#include <cstddef>

#define NNODES 50000

typedef __attribute__((ext_vector_type(8))) short short8;
typedef __attribute__((ext_vector_type(4))) float f32x4;

__device__ __forceinline__ unsigned short f2bf(float f) {
  unsigned u = __builtin_bit_cast(unsigned, f);
  u = u + 0x7FFFu + ((u >> 16) & 1u);
  return (unsigned short)(u >> 16);
}

// ---------------- degree ----------------
__global__ void deg_count_kernel(const int* __restrict__ ei, int E, float* __restrict__ deg) {
  int i = blockIdx.x * blockDim.x + threadIdx.x;
  if (i < E) unsafeAtomicAdd(&deg[ei[E + i]], 1.0f);
}

__global__ void deg_finish_kernel(float* __restrict__ dinv, int n) {
  int i = blockIdx.x * blockDim.x + threadIdx.x;
  if (i < n) dinv[i] = rsqrtf(dinv[i] + 1.0f);  // +1 self-loop
}

// ---------------- W[K][N] fp32 -> Wt[N][K] bf16 ----------------
__global__ void wt_kernel(const float* __restrict__ W, unsigned short* __restrict__ Wt,
                          int logK, int Nc) {
  int idx = blockIdx.x * blockDim.x + threadIdx.x;
  int K = 1 << logK;
  if (idx >= K * Nc) return;
  int n = idx >> logK, k = idx & (K - 1);
  Wt[idx] = f2bf(W[(size_t)k * Nc + n]);
}

// ---------------- bf16 MFMA GEMM, BM=256 BN=64 BK=64, 4 waves ----------------
// A: [M][K] (fp32 if A_FP32 else bf16), Wt: [Nc][K] bf16.
// Epilogue: h' = (A@W)[r][c] * dinv[r];  H[o]=h';  AGG[o]=h'*dinv[r]  (self-loop term)
template <int A_FP32>
__global__ __launch_bounds__(256) void mfma_gemm_kernel(
    const void* __restrict__ Av, const unsigned short* __restrict__ Wt,
    float* __restrict__ H, float* __restrict__ AGG,
    const float* __restrict__ dinv, int M, int K, int Nc) {
  __shared__ unsigned short Alds[256 * 64];  // 32 KB, rows of 64 bf16, XOR-swizzled 16B slots
  __shared__ unsigned short Blds[64 * 64];   // 8 KB
  const int tid = threadIdx.x;
  const int lane = tid & 63;
  const int w = tid >> 6;
  const int n0 = blockIdx.x * 64;
  const int r0 = blockIdx.y * 256;
  const float* Af = (const float*)Av;
  const unsigned short* Ab = (const unsigned short*)Av;

  short8 aReg[8];
  short8 bReg[2];

  auto preload = [&](int k0) {
#pragma unroll
    for (int q = 0; q < 8; q++) {
      int slot = q * 256 + tid;  // 0..2047
      int row = slot >> 3;
      int s = slot & 7;
      int gr = r0 + row;
      if (gr > M - 1) gr = M - 1;  // clamp: no OOB, garbage rows never stored
      if (A_FP32) {
        const float* p = Af + (size_t)gr * K + k0 + s * 8;
        float4 u0 = *(const float4*)p;
        float4 u1 = *(const float4*)(p + 4);
        short8 t;
        t[0] = (short)f2bf(u0.x); t[1] = (short)f2bf(u0.y);
        t[2] = (short)f2bf(u0.z); t[3] = (short)f2bf(u0.w);
        t[4] = (short)f2bf(u1.x); t[5] = (short)f2bf(u1.y);
        t[6] = (short)f2bf(u1.z); t[7] = (short)f2bf(u1.w);
        aReg[q] = t;
      } else {
        aReg[q] = *(const short8*)(Ab + (size_t)gr * K + k0 + s * 8);
      }
    }
#pragma unroll
    for (int q = 0; q < 2; q++) {
      int slot = q * 256 + tid;  // 0..511
      int n = slot >> 3;
      int s = slot & 7;
      bReg[q] = *(const short8*)(Wt + (size_t)(n0 + n) * K + k0 + s * 8);
    }
  };

  auto stage = [&]() {
#pragma unroll
    for (int q = 0; q < 8; q++) {
      int slot = q * 256 + tid;
      int row = slot >> 3;
      int s = slot & 7;
      int sp = s ^ (row & 7);
      *(short8*)&Alds[row * 64 + sp * 8] = aReg[q];
    }
#pragma unroll
    for (int q = 0; q < 2; q++) {
      int slot = q * 256 + tid;
      int n = slot >> 3;
      int s = slot & 7;
      int sp = s ^ (n & 7);
      *(short8*)&Blds[n * 64 + sp * 8] = bReg[q];
    }
  };

  f32x4 acc[4][4] = {};
  preload(0);
  for (int k0 = 0; k0 < K; k0 += 64) {
    __syncthreads();  // previous compute done with LDS
    stage();
    __syncthreads();
    if (k0 + 64 < K) preload(k0 + 64);  // loads in flight during compute
#pragma unroll
    for (int kk = 0; kk < 2; kk++) {
      const int t16 = kk * 4 + (lane >> 4);
      short8 af[4], bf[4];
#pragma unroll
      for (int mi = 0; mi < 4; mi++) {
        int row = w * 64 + mi * 16 + (lane & 15);
        af[mi] = *(const short8*)&Alds[row * 64 + (t16 ^ (row & 7)) * 8];
      }
#pragma unroll
      for (int ni = 0; ni < 4; ni++) {
        int n = ni * 16 + (lane & 15);
        bf[ni] = *(const short8*)&Blds[n * 64 + (t16 ^ (n & 7)) * 8];
      }
#pragma unroll
      for (int mi = 0; mi < 4; mi++)
#pragma unroll
        for (int ni = 0; ni < 4; ni++)
          acc[mi][ni] =
              __builtin_amdgcn_mfma_f32_16x16x32_bf16(af[mi], bf[ni], acc[mi][ni], 0, 0, 0);
    }
  }

  // C/D layout (m89): col = lane&15, row = (lane>>4)*4 + reg
#pragma unroll
  for (int mi = 0; mi < 4; mi++) {
#pragma unroll
    for (int r = 0; r < 4; r++) {
      int gr = r0 + w * 64 + mi * 16 + (lane >> 4) * 4 + r;
      if (gr < M) {
        float di = dinv[gr];
#pragma unroll
        for (int ni = 0; ni < 4; ni++) {
          float hp = acc[mi][ni][r] * di;  // H' = H * dinv[row]
          size_t o = (size_t)gr * Nc + n0 + ni * 16 + (lane & 15);
          H[o] = hp;
          AGG[o] = hp * di;  // self-loop: H * dinv^2
        }
      }
    }
  }
}

// ---------------- edge scatter: AGG[dst] += H'[src] * dinv[dst], float4 ----------------
__global__ void scatter4_kernel(const int* __restrict__ ei, int E,
                                const float* __restrict__ H, float* __restrict__ AGG,
                                const float* __restrict__ dinv, int logc4) {
  size_t idx = (size_t)blockIdx.x * blockDim.x + threadIdx.x;
  size_t total = ((size_t)E) << logc4;
  if (idx >= total) return;
  int e = (int)(idx >> logc4);
  int j4 = (int)(idx & ((1u << logc4) - 1)) * 4;
  int src = ei[e];
  int dst = ei[E + e];
  float norm = dinv[dst];
  float4 h = *(const float4*)&H[((size_t)src << (logc4 + 2)) + j4];
  float* dp = &AGG[((size_t)dst << (logc4 + 2)) + j4];
  unsafeAtomicAdd(dp + 0, h.x * norm);
  unsafeAtomicAdd(dp + 1, h.y * norm);
  unsafeAtomicAdd(dp + 2, h.z * norm);
  unsafeAtomicAdd(dp + 3, h.w * norm);
}

// ---------------- BN(+bias)+ReLU -> bf16 next-layer input ----------------
__global__ void bn_bf16_kernel(const float* __restrict__ AGG,
                               const float* __restrict__ Bb, const float* __restrict__ g,
                               const float* __restrict__ bt, const float* __restrict__ m,
                               const float* __restrict__ v, unsigned short* __restrict__ X,
                               size_t total, int cmask) {
  size_t idx = (size_t)blockIdx.x * blockDim.x + threadIdx.x;
  if (idx >= total) return;
  int j = (int)(idx & (size_t)cmask);
  float a = g[j] * rsqrtf(v[j] + 1e-5f);
  float val = (AGG[idx] + Bb[j] - m[j]) * a + bt[j];
  X[idx] = f2bf(fmaxf(val, 0.0f));
}

// ---------------- layer-3: BN (no relu) fused with mean-pool ----------------
__global__ void bn_pool_kernel(const float* __restrict__ AGG,
                               const float* __restrict__ Bb, const float* __restrict__ g,
                               const float* __restrict__ bt, const float* __restrict__ m,
                               const float* __restrict__ v, int M, float* __restrict__ emb) {
  int ch = threadIdx.x & 63;
  int sub = threadIdx.x >> 6;
  float a = g[ch] * rsqrtf(v[ch] + 1e-5f);
  float sh = (Bb[ch] - m[ch]) * a + bt[ch];
  float acc = 0.0f;
  for (int r = blockIdx.x * 4 + sub; r < M; r += gridDim.x * 4)
    acc += AGG[(size_t)r * 64 + ch] * a + sh;
  __shared__ float red[256];
  red[threadIdx.x] = acc;
  __syncthreads();
  if (sub == 0)
    unsafeAtomicAdd(&emb[ch], red[ch] + red[64 + ch] + red[128 + ch] + red[192 + ch]);
}

// ---------------- head ----------------
__global__ void head_kernel(const float* __restrict__ emb, const float* __restrict__ fuse_W,
                            const float* __restrict__ fuse_b, const float* __restrict__ cls_W,
                            const float* __restrict__ cls_b, const float* __restrict__ reg_W,
                            const float* __restrict__ reg_b, float* __restrict__ out) {
  __shared__ float e[192];
  __shared__ float fused[64];
  int t = threadIdx.x;
  if (t < 192) e[t] = emb[t] * (1.0f / (float)NNODES);
  __syncthreads();
  if (t < 64) {
    float acc = fuse_b[t];
    for (int k = 0; k < 192; k++) acc += e[k] * fuse_W[k * 64 + t];
    fused[t] = fmaxf(acc, 0.0f);
  }
  __syncthreads();
  if (t < 10) {
    float acc = cls_b[t];
    for (int k = 0; k < 64; k++) acc += fused[k] * cls_W[k * 10 + t];
    out[t] = acc;
  }
  if (t == 64) {
    float acc = reg_b[0];
    for (int k = 0; k < 64; k++) acc += fused[k] * reg_W[k];
    out[10] = 1.0f / (1.0f + expf(-acc));
  }
}

extern "C" void kernel_launch(void* const* d_in, const int* in_sizes, int n_in,
                              void* d_out, int out_size, void* d_ws, size_t ws_size,
                              hipStream_t stream) {
  const int N = NNODES;
  const float* xs[3] = {(const float*)d_in[0], (const float*)d_in[1], (const float*)d_in[2]};
  const int* eis[3] = {(const int*)d_in[3], (const int*)d_in[4], (const int*)d_in[5]};
  int Es[3];
  for (int s = 0; s < 3; s++) Es[s] = in_sizes[3 + s] / 2;

  const float* Wp[3]  = {(const float*)d_in[6],  (const float*)d_in[12], (const float*)d_in[18]};
  const float* Bp[3]  = {(const float*)d_in[7],  (const float*)d_in[13], (const float*)d_in[19]};
  const float* gp[3]  = {(const float*)d_in[8],  (const float*)d_in[14], (const float*)d_in[20]};
  const float* btp[3] = {(const float*)d_in[9],  (const float*)d_in[15], (const float*)d_in[21]};
  const float* mp[3]  = {(const float*)d_in[10], (const float*)d_in[16], (const float*)d_in[22]};
  const float* vp[3]  = {(const float*)d_in[11], (const float*)d_in[17], (const float*)d_in[23]};
  const float* fuse_W = (const float*)d_in[24];
  const float* fuse_b = (const float*)d_in[25];
  const float* cls_W  = (const float*)d_in[26];
  const float* cls_b  = (const float*)d_in[27];
  const float* reg_W  = (const float*)d_in[28];
  const float* reg_b  = (const float*)d_in[29];

  const int logKs[3] = {10, 8, 7};  // K = 1024, 256, 128
  const int douts[3] = {256, 128, 64};
  const int logc4s[3] = {6, 5, 4};  // log2(C/4)

  size_t off = 0;
  auto alloc = [&](size_t nbytes) {
    char* p = (char*)d_ws + off;
    off += (nbytes + 255) & ~(size_t)255;
    return (void*)p;
  };
  float* dinv_all = (float*)alloc(3 * (size_t)N * 4);
  float* emb      = (float*)alloc(192 * 4);
  float* Hbuf     = (float*)alloc((size_t)N * 256 * 4);   // 51.2 MB
  float* AGG      = (float*)alloc((size_t)N * 256 * 4);   // 51.2 MB
  unsigned short* Xbf = (unsigned short*)alloc((size_t)N * 256 * 2);  // 25.6 MB
  unsigned short* Wt  = (unsigned short*)alloc((size_t)1024 * 256 * 2);
  (void)ws_size; (void)n_in; (void)out_size;

  hipMemsetAsync(dinv_all, 0, 3 * (size_t)N * 4, stream);
  hipMemsetAsync(emb, 0, 192 * 4, stream);

  for (int s = 0; s < 3; s++)
    deg_count_kernel<<<(Es[s] + 255) / 256, 256, 0, stream>>>(eis[s], Es[s],
                                                              dinv_all + (size_t)s * N);
  deg_finish_kernel<<<(3 * N + 255) / 256, 256, 0, stream>>>(dinv_all, 3 * N);

  const int MB = (N + 255) / 256;  // 196
  for (int s = 0; s < 3; s++) {
    const float* dinv = dinv_all + (size_t)s * N;
    for (int l = 0; l < 3; l++) {
      int logK = logKs[l], K = 1 << logK, C = douts[l];
      const float* W  = Wp[l]  + (size_t)s * K * C;
      const float* Bb = Bp[l]  + (size_t)s * C;
      const float* g  = gp[l]  + (size_t)s * C;
      const float* bt = btp[l] + (size_t)s * C;
      const float* m  = mp[l]  + (size_t)s * C;
      const float* v  = vp[l]  + (size_t)s * C;

      wt_kernel<<<(K * C + 255) / 256, 256, 0, stream>>>(W, Wt, logK, C);

      dim3 grid(C / 64, MB);
      if (l == 0)
        mfma_gemm_kernel<1><<<grid, 256, 0, stream>>>(xs[s], Wt, Hbuf, AGG, dinv, N, K, C);
      else
        mfma_gemm_kernel<0><<<grid, 256, 0, stream>>>(Xbf, Wt, Hbuf, AGG, dinv, N, K, C);

      size_t total = ((size_t)Es[s]) << logc4s[l];
      scatter4_kernel<<<(unsigned)((total + 255) / 256), 256, 0, stream>>>(
          eis[s], Es[s], Hbuf, AGG, dinv, logc4s[l]);

      if (l < 2) {
        size_t tot2 = (size_t)N * C;
        bn_bf16_kernel<<<(unsigned)((tot2 + 255) / 256), 256, 0, stream>>>(
            AGG, Bb, g, bt, m, v, Xbf, tot2, C - 1);
      } else {
        bn_pool_kernel<<<256, 256, 0, stream>>>(AGG, Bb, g, bt, m, v, N, emb + s * 64);
      }
    }
  }

  head_kernel<<<1, 192, 0, stream>>>(emb, fuse_W, fuse_b, cls_W, cls_b, reg_W, reg_b,
                                     (float*)d_out);
}

// Round 4
// 1658.794 us; speedup vs baseline: 4.2103x; 4.2103x over previous
//
#include <hip/hip_runtime.h>
#include <cstdint>
#include <cstddef>

#define NNODES 50000

typedef __attribute__((ext_vector_type(8))) short short8;
typedef __attribute__((ext_vector_type(4))) float f32x4;
typedef __attribute__((ext_vector_type(4))) unsigned short u16x4;
typedef __attribute__((ext_vector_type(2))) unsigned short u16x2;

__device__ __forceinline__ unsigned short f2bf(float f) {
  unsigned u = __builtin_bit_cast(unsigned, f);
  u = u + 0x7FFFu + ((u >> 16) & 1u);
  return (unsigned short)(u >> 16);
}
__device__ __forceinline__ float bf2f(unsigned short u) {
  return __builtin_bit_cast(float, (unsigned)u << 16);
}

// ---------------- degree (int counts) ----------------
__global__ void deg_count_kernel(const int* __restrict__ ei, int E, int* __restrict__ deg) {
  int i = blockIdx.x * blockDim.x + threadIdx.x;
  if (i < E) atomicAdd(&deg[ei[E + i]], 1);
}

__global__ void deg_finish_kernel(const int* __restrict__ deg, float* __restrict__ dinv, int n) {
  int i = blockIdx.x * blockDim.x + threadIdx.x;
  if (i < n) dinv[i] = rsqrtf((float)deg[i] + 1.0f);  // +1 self-loop
}

// ---------------- exclusive scan (single block, 1024 thr) ----------------
// rowptr[0]=0, rowptr[i+1]=incl[i]; cursor[i]=rowptr[i]
__global__ void scan_kernel(const int* __restrict__ deg, int* __restrict__ rowptr,
                            int* __restrict__ cursor, int n) {
  __shared__ int tmp[1024];
  __shared__ int carry;
  const int tid = threadIdx.x;
  if (tid == 0) { carry = 0; rowptr[0] = 0; }
  __syncthreads();
  for (int base = 0; base < n; base += 1024) {
    int i = base + tid;
    int val = (i < n) ? deg[i] : 0;
    tmp[tid] = val;
    __syncthreads();
    for (int off = 1; off < 1024; off <<= 1) {
      int t = (tid >= off) ? tmp[tid - off] : 0;
      __syncthreads();
      tmp[tid] += t;
      __syncthreads();
    }
    int inc = tmp[tid] + carry;
    if (i < n) { rowptr[i + 1] = inc; cursor[i] = inc - val; }
    __syncthreads();
    if (tid == 1023) carry = inc;
    __syncthreads();
  }
}

// ---------------- CSR fill ----------------
__global__ void csr_fill_kernel(const int* __restrict__ ei, int E, int* __restrict__ cursor,
                                int* __restrict__ csr) {
  int i = blockIdx.x * blockDim.x + threadIdx.x;
  if (i < E) {
    int src = ei[i];
    int dst = ei[E + i];
    int pos = atomicAdd(&cursor[dst], 1);
    if (pos < E) csr[pos] = src;
  }
}

// ---------------- W[K][N] fp32 -> Wt[N][K] bf16 ----------------
__global__ void wt_kernel(const float* __restrict__ W, unsigned short* __restrict__ Wt,
                          int logK, int Nc) {
  int idx = blockIdx.x * blockDim.x + threadIdx.x;
  int K = 1 << logK;
  if (idx >= K * Nc) return;
  int n = idx >> logK, k = idx & (K - 1);
  Wt[idx] = f2bf(W[(size_t)k * Nc + n]);
}

// ---------------- bf16 MFMA GEMM, BM=256 BN=64 BK=64, 4 waves ----------------
// A: [M][K] (fp32 if A_FP32 else bf16), Wt: [Nc][K] bf16.
// Epilogue: H'[r][c] = (A@W)[r][c] * dinv[r], stored bf16.
template <int A_FP32>
__global__ __launch_bounds__(256) void mfma_gemm_kernel(
    const void* __restrict__ Av, const unsigned short* __restrict__ Wt,
    unsigned short* __restrict__ H, const float* __restrict__ dinv, int M, int K, int Nc) {
  __shared__ unsigned short Alds[256 * 64];
  __shared__ unsigned short Blds[64 * 64];
  const int tid = threadIdx.x;
  const int lane = tid & 63;
  const int w = tid >> 6;
  const int n0 = blockIdx.x * 64;
  const int r0 = blockIdx.y * 256;
  const float* Af = (const float*)Av;
  const unsigned short* Ab = (const unsigned short*)Av;

  short8 aReg[8];
  short8 bReg[2];

  auto preload = [&](int k0) {
#pragma unroll
    for (int q = 0; q < 8; q++) {
      int slot = q * 256 + tid;
      int row = slot >> 3;
      int s = slot & 7;
      int gr = r0 + row;
      if (gr > M - 1) gr = M - 1;
      if (A_FP32) {
        const float* p = Af + (size_t)gr * K + k0 + s * 8;
        float4 u0 = *(const float4*)p;
        float4 u1 = *(const float4*)(p + 4);
        short8 t;
        t[0] = (short)f2bf(u0.x); t[1] = (short)f2bf(u0.y);
        t[2] = (short)f2bf(u0.z); t[3] = (short)f2bf(u0.w);
        t[4] = (short)f2bf(u1.x); t[5] = (short)f2bf(u1.y);
        t[6] = (short)f2bf(u1.z); t[7] = (short)f2bf(u1.w);
        aReg[q] = t;
      } else {
        aReg[q] = *(const short8*)(Ab + (size_t)gr * K + k0 + s * 8);
      }
    }
#pragma unroll
    for (int q = 0; q < 2; q++) {
      int slot = q * 256 + tid;
      int n = slot >> 3;
      int s = slot & 7;
      bReg[q] = *(const short8*)(Wt + (size_t)(n0 + n) * K + k0 + s * 8);
    }
  };

  auto stage = [&]() {
#pragma unroll
    for (int q = 0; q < 8; q++) {
      int slot = q * 256 + tid;
      int row = slot >> 3;
      int s = slot & 7;
      *(short8*)&Alds[row * 64 + (s ^ (row & 7)) * 8] = aReg[q];
    }
#pragma unroll
    for (int q = 0; q < 2; q++) {
      int slot = q * 256 + tid;
      int n = slot >> 3;
      int s = slot & 7;
      *(short8*)&Blds[n * 64 + (s ^ (n & 7)) * 8] = bReg[q];
    }
  };

  f32x4 acc[4][4] = {};
  preload(0);
  for (int k0 = 0; k0 < K; k0 += 64) {
    __syncthreads();
    stage();
    __syncthreads();
    if (k0 + 64 < K) preload(k0 + 64);
#pragma unroll
    for (int kk = 0; kk < 2; kk++) {
      const int t16 = kk * 4 + (lane >> 4);
      short8 af[4], bfr[4];
#pragma unroll
      for (int mi = 0; mi < 4; mi++) {
        int row = w * 64 + mi * 16 + (lane & 15);
        af[mi] = *(const short8*)&Alds[row * 64 + (t16 ^ (row & 7)) * 8];
      }
#pragma unroll
      for (int ni = 0; ni < 4; ni++) {
        int n = ni * 16 + (lane & 15);
        bfr[ni] = *(const short8*)&Blds[n * 64 + (t16 ^ (n & 7)) * 8];
      }
#pragma unroll
      for (int mi = 0; mi < 4; mi++)
#pragma unroll
        for (int ni = 0; ni < 4; ni++)
          acc[mi][ni] =
              __builtin_amdgcn_mfma_f32_16x16x32_bf16(af[mi], bfr[ni], acc[mi][ni], 0, 0, 0);
    }
  }

  // C/D layout: col = lane&15, row = (lane>>4)*4 + reg
#pragma unroll
  for (int mi = 0; mi < 4; mi++) {
#pragma unroll
    for (int r = 0; r < 4; r++) {
      int gr = r0 + w * 64 + mi * 16 + (lane >> 4) * 4 + r;
      if (gr < M) {
        float di = dinv[gr];
#pragma unroll
        for (int ni = 0; ni < 4; ni++)
          H[(size_t)gr * Nc + n0 + ni * 16 + (lane & 15)] = f2bf(acc[mi][ni][r] * di);
      }
    }
  }
}

// ---------------- CSR gather + BN(+ReLU) (+pool) ----------------
template <int VEC>
__device__ __forceinline__ void addrow(const unsigned short* __restrict__ p, float* acc) {
  if constexpr (VEC == 4) {
    u16x4 u = *(const u16x4*)p;
#pragma unroll
    for (int j = 0; j < 4; j++) acc[j] += bf2f(u[j]);
  } else if constexpr (VEC == 2) {
    u16x2 u = *(const u16x2*)p;
    acc[0] += bf2f(u[0]);
    acc[1] += bf2f(u[1]);
  } else {
    acc[0] += bf2f(*p);
  }
}

// out_row = dinv[row] * (H'[row] + sum_{src in csr} H'[src]); then BN(+ReLU)->bf16,
// or (POOL) BN (no relu) accumulated into emb.
template <int VEC, int POOL>
__global__ __launch_bounds__(256) void agg_kernel(
    const unsigned short* __restrict__ Hb, const int* __restrict__ rowptr,
    const int* __restrict__ csr, const float* __restrict__ dinv,
    const float* __restrict__ Bb, const float* __restrict__ g,
    const float* __restrict__ bt, const float* __restrict__ m,
    const float* __restrict__ v, unsigned short* __restrict__ X,
    float* __restrict__ emb, int n) {
  const int C = VEC * 64;
  const int lane = threadIdx.x & 63;
  const int w = threadIdx.x >> 6;
  const int ch = lane * VEC;
  float a[VEC], sh[VEC];
#pragma unroll
  for (int j = 0; j < VEC; j++) {
    float aa = g[ch + j] * rsqrtf(v[ch + j] + 1e-5f);
    a[j] = aa;
    sh[j] = (Bb[ch + j] - m[ch + j]) * aa + bt[ch + j];
  }
  float pool = 0.0f;
  const int row0 = blockIdx.x * 4 + w;
  const int stride = POOL ? (int)(gridDim.x * 4) : n;
  for (int row = row0; row < n; row += stride) {
    float acc[VEC] = {};
    addrow<VEC>(Hb + (size_t)row * C + ch, acc);  // self
    int b0 = rowptr[row], b1 = rowptr[row + 1];
    int i = b0;
    for (; i + 4 <= b1; i += 4) {
      int s0 = csr[i], s1 = csr[i + 1], s2 = csr[i + 2], s3 = csr[i + 3];
      addrow<VEC>(Hb + (size_t)s0 * C + ch, acc);
      addrow<VEC>(Hb + (size_t)s1 * C + ch, acc);
      addrow<VEC>(Hb + (size_t)s2 * C + ch, acc);
      addrow<VEC>(Hb + (size_t)s3 * C + ch, acc);
    }
    for (; i < b1; i++) addrow<VEC>(Hb + (size_t)csr[i] * C + ch, acc);
    float dd = dinv[row];
    if constexpr (!POOL) {
      if constexpr (VEC == 4) {
        u16x4 o;
#pragma unroll
        for (int j = 0; j < 4; j++) o[j] = f2bf(fmaxf(acc[j] * dd * a[j] + sh[j], 0.0f));
        *(u16x4*)(X + (size_t)row * C + ch) = o;
      } else if constexpr (VEC == 2) {
        u16x2 o;
        o[0] = f2bf(fmaxf(acc[0] * dd * a[0] + sh[0], 0.0f));
        o[1] = f2bf(fmaxf(acc[1] * dd * a[1] + sh[1], 0.0f));
        *(u16x2*)(X + (size_t)row * C + ch) = o;
      } else {
        X[(size_t)row * C + ch] = f2bf(fmaxf(acc[0] * dd * a[0] + sh[0], 0.0f));
      }
    } else {
      pool += acc[0] * dd * a[0] + sh[0];  // VEC==1, no relu
    }
  }
  if constexpr (POOL) {
    __shared__ float red[256];
    red[threadIdx.x] = pool;
    __syncthreads();
    if (w == 0)
      unsafeAtomicAdd(&emb[lane], red[lane] + red[64 + lane] + red[128 + lane] + red[192 + lane]);
  }
}

// ---------------- head ----------------
__global__ void head_kernel(const float* __restrict__ emb, const float* __restrict__ fuse_W,
                            const float* __restrict__ fuse_b, const float* __restrict__ cls_W,
                            const float* __restrict__ cls_b, const float* __restrict__ reg_W,
                            const float* __restrict__ reg_b, float* __restrict__ out) {
  __shared__ float e[192];
  __shared__ float fused[64];
  int t = threadIdx.x;
  if (t < 192) e[t] = emb[t] * (1.0f / (float)NNODES);
  __syncthreads();
  if (t < 64) {
    float acc = fuse_b[t];
    for (int k = 0; k < 192; k++) acc += e[k] * fuse_W[k * 64 + t];
    fused[t] = fmaxf(acc, 0.0f);
  }
  __syncthreads();
  if (t < 10) {
    float acc = cls_b[t];
    for (int k = 0; k < 64; k++) acc += fused[k] * cls_W[k * 10 + t];
    out[t] = acc;
  }
  if (t == 64) {
    float acc = reg_b[0];
    for (int k = 0; k < 64; k++) acc += fused[k] * reg_W[k];
    out[10] = 1.0f / (1.0f + expf(-acc));
  }
}

extern "C" void kernel_launch(void* const* d_in, const int* in_sizes, int n_in,
                              void* d_out, int out_size, void* d_ws, size_t ws_size,
                              hipStream_t stream) {
  const int N = NNODES;
  const float* xs[3] = {(const float*)d_in[0], (const float*)d_in[1], (const float*)d_in[2]};
  const int* eis[3] = {(const int*)d_in[3], (const int*)d_in[4], (const int*)d_in[5]};
  int Es[3];
  for (int s = 0; s < 3; s++) Es[s] = in_sizes[3 + s] / 2;

  const float* Wp[3]  = {(const float*)d_in[6],  (const float*)d_in[12], (const float*)d_in[18]};
  const float* Bp[3]  = {(const float*)d_in[7],  (const float*)d_in[13], (const float*)d_in[19]};
  const float* gp[3]  = {(const float*)d_in[8],  (const float*)d_in[14], (const float*)d_in[20]};
  const float* btp[3] = {(const float*)d_in[9],  (const float*)d_in[15], (const float*)d_in[21]};
  const float* mp[3]  = {(const float*)d_in[10], (const float*)d_in[16], (const float*)d_in[22]};
  const float* vp[3]  = {(const float*)d_in[11], (const float*)d_in[17], (const float*)d_in[23]};
  const float* fuse_W = (const float*)d_in[24];
  const float* fuse_b = (const float*)d_in[25];
  const float* cls_W  = (const float*)d_in[26];
  const float* cls_b  = (const float*)d_in[27];
  const float* reg_W  = (const float*)d_in[28];
  const float* reg_b  = (const float*)d_in[29];

  const int logKs[3] = {10, 8, 7};
  const int douts[3] = {256, 128, 64};

  size_t off = 0;
  auto alloc = [&](size_t nbytes) {
    char* p = (char*)d_ws + off;
    off += (nbytes + 255) & ~(size_t)255;
    return (void*)p;
  };
  int*   deg      = (int*)alloc(3 * (size_t)N * 4);
  float* dinv_all = (float*)alloc(3 * (size_t)N * 4);
  float* emb      = (float*)alloc(192 * 4);
  int*   rowptr   = (int*)alloc((size_t)(N + 1) * 4);
  int*   cursor   = (int*)alloc((size_t)N * 4);
  int*   csr      = (int*)alloc((size_t)600000 * 4);
  unsigned short* Hbuf = (unsigned short*)alloc((size_t)N * 256 * 2);  // 25.6 MB
  unsigned short* Xbf  = (unsigned short*)alloc((size_t)N * 256 * 2);  // 25.6 MB
  unsigned short* Wt   = (unsigned short*)alloc((size_t)1024 * 256 * 2);
  (void)ws_size; (void)n_in; (void)out_size;

  hipMemsetAsync(deg, 0, 3 * (size_t)N * 4, stream);
  hipMemsetAsync(emb, 0, 192 * 4, stream);

  for (int s = 0; s < 3; s++)
    deg_count_kernel<<<(Es[s] + 255) / 256, 256, 0, stream>>>(eis[s], Es[s], deg + (size_t)s * N);
  deg_finish_kernel<<<(3 * N + 255) / 256, 256, 0, stream>>>(deg, dinv_all, 3 * N);

  const int MB = (N + 255) / 256;  // 196
  for (int s = 0; s < 3; s++) {
    const float* dinv = dinv_all + (size_t)s * N;
    scan_kernel<<<1, 1024, 0, stream>>>(deg + (size_t)s * N, rowptr, cursor, N);
    csr_fill_kernel<<<(Es[s] + 255) / 256, 256, 0, stream>>>(eis[s], Es[s], cursor, csr);

    for (int l = 0; l < 3; l++) {
      int logK = logKs[l], K = 1 << logK, C = douts[l];
      const float* W  = Wp[l]  + (size_t)s * K * C;
      const float* Bb = Bp[l]  + (size_t)s * C;
      const float* g  = gp[l]  + (size_t)s * C;
      const float* bt = btp[l] + (size_t)s * C;
      const float* m  = mp[l]  + (size_t)s * C;
      const float* v  = vp[l]  + (size_t)s * C;

      wt_kernel<<<(K * C + 255) / 256, 256, 0, stream>>>(W, Wt, logK, C);

      dim3 grid(C / 64, MB);
      if (l == 0)
        mfma_gemm_kernel<1><<<grid, 256, 0, stream>>>(xs[s], Wt, Hbuf, dinv, N, K, C);
      else
        mfma_gemm_kernel<0><<<grid, 256, 0, stream>>>(Xbf, Wt, Hbuf, dinv, N, K, C);

      if (l == 0)
        agg_kernel<4, 0><<<(N + 3) / 4, 256, 0, stream>>>(Hbuf, rowptr, csr, dinv, Bb, g, bt, m,
                                                          v, Xbf, emb, N);
      else if (l == 1)
        agg_kernel<2, 0><<<(N + 3) / 4, 256, 0, stream>>>(Hbuf, rowptr, csr, dinv, Bb, g, bt, m,
                                                          v, Xbf, emb, N);
      else
        agg_kernel<1, 1><<<128, 256, 0, stream>>>(Hbuf, rowptr, csr, dinv, Bb, g, bt, m, v, Xbf,
                                                  emb + s * 64, N);
    }
  }

  head_kernel<<<1, 192, 0, stream>>>(emb, fuse_W, fuse_b, cls_W, cls_b, reg_W, reg_b,
                                     (float*)d_out);
}

// Round 5
// 1222.580 us; speedup vs baseline: 5.7125x; 1.3568x over previous
//
#include <hip/hip_runtime.h>
#include <cstdint>
#include <cstddef>

#define NNODES 50000

typedef __attribute__((ext_vector_type(8))) short short8;
typedef __attribute__((ext_vector_type(4))) float f32x4;
typedef __attribute__((ext_vector_type(4))) unsigned short u16x4;
typedef __attribute__((ext_vector_type(2))) unsigned short u16x2;

__device__ __forceinline__ unsigned short f2bf(float f) {
  unsigned u = __builtin_bit_cast(unsigned, f);
  u = u + 0x7FFFu + ((u >> 16) & 1u);
  return (unsigned short)(u >> 16);
}
__device__ __forceinline__ float bf2f(unsigned short u) {
  return __builtin_bit_cast(float, (unsigned)u << 16);
}

// ---------------- degree (int counts) ----------------
__global__ void deg_count_kernel(const int* __restrict__ ei, int E, int* __restrict__ deg) {
  int i = blockIdx.x * blockDim.x + threadIdx.x;
  if (i < E) atomicAdd(&deg[ei[E + i]], 1);
}

__global__ void deg_finish_kernel(const int* __restrict__ deg, float* __restrict__ dinv, int n) {
  int i = blockIdx.x * blockDim.x + threadIdx.x;
  if (i < n) dinv[i] = rsqrtf((float)deg[i] + 1.0f);  // +1 self-loop
}

// ---------------- pool-weight c[j] = dinv[j]*(dinv[j] + sum_{edges src=j} dinv[dst]) --------
__global__ void csum_count_kernel(const int* __restrict__ ei, int E,
                                  const float* __restrict__ dinv, float* __restrict__ csum) {
  int i = blockIdx.x * blockDim.x + threadIdx.x;
  if (i < E) unsafeAtomicAdd(&csum[ei[i]], dinv[ei[E + i]]);
}

__global__ void c_finish_kernel(const float* __restrict__ dinv, float* __restrict__ csum, int n) {
  int i = blockIdx.x * blockDim.x + threadIdx.x;
  if (i < n) csum[i] = dinv[i] * (dinv[i] + csum[i]);
}

// ---------------- exclusive scan (single block, 1024 thr) ----------------
__global__ void scan_kernel(const int* __restrict__ deg, int* __restrict__ rowptr,
                            int* __restrict__ cursor, int n) {
  __shared__ int tmp[1024];
  __shared__ int carry;
  const int tid = threadIdx.x;
  if (tid == 0) { carry = 0; rowptr[0] = 0; }
  __syncthreads();
  for (int base = 0; base < n; base += 1024) {
    int i = base + tid;
    int val = (i < n) ? deg[i] : 0;
    tmp[tid] = val;
    __syncthreads();
    for (int off = 1; off < 1024; off <<= 1) {
      int t = (tid >= off) ? tmp[tid - off] : 0;
      __syncthreads();
      tmp[tid] += t;
      __syncthreads();
    }
    int inc = tmp[tid] + carry;
    if (i < n) { rowptr[i + 1] = inc; cursor[i] = inc - val; }
    __syncthreads();
    if (tid == 1023) carry = inc;
    __syncthreads();
  }
}

// ---------------- CSR fill ----------------
__global__ void csr_fill_kernel(const int* __restrict__ ei, int E, int* __restrict__ cursor,
                                int* __restrict__ csr) {
  int i = blockIdx.x * blockDim.x + threadIdx.x;
  if (i < E) {
    int src = ei[i];
    int dst = ei[E + i];
    int pos = atomicAdd(&cursor[dst], 1);
    if (pos < E) csr[pos] = src;
  }
}

// ---------------- W[K][N] fp32 -> Wt[N][K] bf16 ----------------
__global__ void wt_kernel(const float* __restrict__ W, unsigned short* __restrict__ Wt,
                          int logK, int Nc) {
  int idx = blockIdx.x * blockDim.x + threadIdx.x;
  int K = 1 << logK;
  if (idx >= K * Nc) return;
  int n = idx >> logK, k = idx & (K - 1);
  Wt[idx] = f2bf(W[(size_t)k * Nc + n]);
}

// ---------------- bf16 MFMA GEMM, BM=256 BN=64 BK=64, 4 waves ----------------
template <int A_FP32>
__global__ __launch_bounds__(256) void mfma_gemm_kernel(
    const void* __restrict__ Av, const unsigned short* __restrict__ Wt,
    unsigned short* __restrict__ H, const float* __restrict__ dinv, int M, int K, int Nc) {
  __shared__ unsigned short Alds[256 * 64];
  __shared__ unsigned short Blds[64 * 64];
  const int tid = threadIdx.x;
  const int lane = tid & 63;
  const int w = tid >> 6;
  const int n0 = blockIdx.x * 64;
  const int r0 = blockIdx.y * 256;
  const float* Af = (const float*)Av;
  const unsigned short* Ab = (const unsigned short*)Av;

  short8 aReg[8];
  short8 bReg[2];

  auto preload = [&](int k0) {
#pragma unroll
    for (int q = 0; q < 8; q++) {
      int slot = q * 256 + tid;
      int row = slot >> 3;
      int s = slot & 7;
      int gr = r0 + row;
      if (gr > M - 1) gr = M - 1;
      if (A_FP32) {
        const float* p = Af + (size_t)gr * K + k0 + s * 8;
        float4 u0 = *(const float4*)p;
        float4 u1 = *(const float4*)(p + 4);
        short8 t;
        t[0] = (short)f2bf(u0.x); t[1] = (short)f2bf(u0.y);
        t[2] = (short)f2bf(u0.z); t[3] = (short)f2bf(u0.w);
        t[4] = (short)f2bf(u1.x); t[5] = (short)f2bf(u1.y);
        t[6] = (short)f2bf(u1.z); t[7] = (short)f2bf(u1.w);
        aReg[q] = t;
      } else {
        aReg[q] = *(const short8*)(Ab + (size_t)gr * K + k0 + s * 8);
      }
    }
#pragma unroll
    for (int q = 0; q < 2; q++) {
      int slot = q * 256 + tid;
      int n = slot >> 3;
      int s = slot & 7;
      bReg[q] = *(const short8*)(Wt + (size_t)(n0 + n) * K + k0 + s * 8);
    }
  };

  auto stage = [&]() {
#pragma unroll
    for (int q = 0; q < 8; q++) {
      int slot = q * 256 + tid;
      int row = slot >> 3;
      int s = slot & 7;
      *(short8*)&Alds[row * 64 + (s ^ (row & 7)) * 8] = aReg[q];
    }
#pragma unroll
    for (int q = 0; q < 2; q++) {
      int slot = q * 256 + tid;
      int n = slot >> 3;
      int s = slot & 7;
      *(short8*)&Blds[n * 64 + (s ^ (n & 7)) * 8] = bReg[q];
    }
  };

  f32x4 acc[4][4] = {};
  preload(0);
  for (int k0 = 0; k0 < K; k0 += 64) {
    __syncthreads();
    stage();
    __syncthreads();
    if (k0 + 64 < K) preload(k0 + 64);
#pragma unroll
    for (int kk = 0; kk < 2; kk++) {
      const int t16 = kk * 4 + (lane >> 4);
      short8 af[4], bfr[4];
#pragma unroll
      for (int mi = 0; mi < 4; mi++) {
        int row = w * 64 + mi * 16 + (lane & 15);
        af[mi] = *(const short8*)&Alds[row * 64 + (t16 ^ (row & 7)) * 8];
      }
#pragma unroll
      for (int ni = 0; ni < 4; ni++) {
        int n = ni * 16 + (lane & 15);
        bfr[ni] = *(const short8*)&Blds[n * 64 + (t16 ^ (n & 7)) * 8];
      }
#pragma unroll
      for (int mi = 0; mi < 4; mi++)
#pragma unroll
        for (int ni = 0; ni < 4; ni++)
          acc[mi][ni] =
              __builtin_amdgcn_mfma_f32_16x16x32_bf16(af[mi], bfr[ni], acc[mi][ni], 0, 0, 0);
    }
  }

#pragma unroll
  for (int mi = 0; mi < 4; mi++) {
#pragma unroll
    for (int r = 0; r < 4; r++) {
      int gr = r0 + w * 64 + mi * 16 + (lane >> 4) * 4 + r;
      if (gr < M) {
        float di = dinv[gr];
#pragma unroll
        for (int ni = 0; ni < 4; ni++)
          H[(size_t)gr * Nc + n0 + ni * 16 + (lane & 15)] = f2bf(acc[mi][ni][r] * di);
      }
    }
  }
}

// ---------------- CSR gather + BN + ReLU -> bf16 ----------------
template <int VEC>
__device__ __forceinline__ void addrow(const unsigned short* __restrict__ p, float* acc) {
  if constexpr (VEC == 4) {
    u16x4 u = *(const u16x4*)p;
#pragma unroll
    for (int j = 0; j < 4; j++) acc[j] += bf2f(u[j]);
  } else {
    u16x2 u = *(const u16x2*)p;
    acc[0] += bf2f(u[0]);
    acc[1] += bf2f(u[1]);
  }
}

template <int VEC>
__global__ __launch_bounds__(256) void agg_kernel(
    const unsigned short* __restrict__ Hb, const int* __restrict__ rowptr,
    const int* __restrict__ csr, const float* __restrict__ dinv,
    const float* __restrict__ Bb, const float* __restrict__ g,
    const float* __restrict__ bt, const float* __restrict__ m,
    const float* __restrict__ v, unsigned short* __restrict__ X, int n) {
  const int C = VEC * 64;
  const int lane = threadIdx.x & 63;
  const int w = threadIdx.x >> 6;
  const int ch = lane * VEC;
  float a[VEC], sh[VEC];
#pragma unroll
  for (int j = 0; j < VEC; j++) {
    float aa = g[ch + j] * rsqrtf(v[ch + j] + 1e-5f);
    a[j] = aa;
    sh[j] = (Bb[ch + j] - m[ch + j]) * aa + bt[ch + j];
  }
  const int row = blockIdx.x * 4 + w;
  if (row >= n) return;
  float acc[VEC] = {};
  addrow<VEC>(Hb + (size_t)row * C + ch, acc);  // self
  int b0 = rowptr[row], b1 = rowptr[row + 1];
  int i = b0;
  for (; i + 4 <= b1; i += 4) {
    int s0 = csr[i], s1 = csr[i + 1], s2 = csr[i + 2], s3 = csr[i + 3];
    addrow<VEC>(Hb + (size_t)s0 * C + ch, acc);
    addrow<VEC>(Hb + (size_t)s1 * C + ch, acc);
    addrow<VEC>(Hb + (size_t)s2 * C + ch, acc);
    addrow<VEC>(Hb + (size_t)s3 * C + ch, acc);
  }
  for (; i < b1; i++) addrow<VEC>(Hb + (size_t)csr[i] * C + ch, acc);
  float dd = dinv[row];
  if constexpr (VEC == 4) {
    u16x4 o;
#pragma unroll
    for (int j = 0; j < 4; j++) o[j] = f2bf(fmaxf(acc[j] * dd * a[j] + sh[j], 0.0f));
    *(u16x4*)(X + (size_t)row * C + ch) = o;
  } else {
    u16x2 o;
    o[0] = f2bf(fmaxf(acc[0] * dd * a[0] + sh[0], 0.0f));
    o[1] = f2bf(fmaxf(acc[1] * dd * a[1] + sh[1], 0.0f));
    *(u16x2*)(X + (size_t)row * C + ch) = o;
  }
}

// ---------------- weighted column-sum: pooled[ch] = sum_j c[j] * X2[j][ch], C=128 -------
__global__ __launch_bounds__(256) void colsum_kernel(const unsigned short* __restrict__ X,
                                                     const float* __restrict__ c,
                                                     float* __restrict__ pooled, int n) {
  const int ch = threadIdx.x & 127;
  const int half = threadIdx.x >> 7;
  float acc = 0.0f;
  for (int row = blockIdx.x * 2 + half; row < n; row += gridDim.x * 2)
    acc += c[row] * bf2f(X[(size_t)row * 128 + ch]);
  __shared__ float red[256];
  red[threadIdx.x] = acc;
  __syncthreads();
  if (threadIdx.x < 128)
    unsafeAtomicAdd(&pooled[ch], red[threadIdx.x] + red[threadIdx.x + 128]);
}

// ---------------- head: per-scale BN3((pooled/N)@W3 + b3), fuse, cls, reg ----------------
__global__ void head_kernel(const float* __restrict__ pooled, const float* __restrict__ W3p,
                            const float* __restrict__ B3p, const float* __restrict__ g3p,
                            const float* __restrict__ bt3p, const float* __restrict__ m3p,
                            const float* __restrict__ v3p, const float* __restrict__ fuse_W,
                            const float* __restrict__ fuse_b, const float* __restrict__ cls_W,
                            const float* __restrict__ cls_b, const float* __restrict__ reg_W,
                            const float* __restrict__ reg_b, float* __restrict__ out) {
  __shared__ float e[192];
  __shared__ float fused[64];
  int t = threadIdx.x;
  if (t < 192) {
    int s = t >> 6, ch = t & 63;
    float acc = 0.0f;
    const float* W3 = W3p + (size_t)s * 128 * 64;
    const float* pv = pooled + s * 128;
    for (int k = 0; k < 128; k++) acc += pv[k] * W3[k * 64 + ch];
    float a3 = g3p[s * 64 + ch] * rsqrtf(v3p[s * 64 + ch] + 1e-5f);
    e[t] = (acc * (1.0f / (float)NNODES) + B3p[s * 64 + ch] - m3p[s * 64 + ch]) * a3 +
           bt3p[s * 64 + ch];
  }
  __syncthreads();
  if (t < 64) {
    float acc = fuse_b[t];
    for (int k = 0; k < 192; k++) acc += e[k] * fuse_W[k * 64 + t];
    fused[t] = fmaxf(acc, 0.0f);
  }
  __syncthreads();
  if (t < 10) {
    float acc = cls_b[t];
    for (int k = 0; k < 64; k++) acc += fused[k] * cls_W[k * 10 + t];
    out[t] = acc;
  }
  if (t == 64) {
    float acc = reg_b[0];
    for (int k = 0; k < 64; k++) acc += fused[k] * reg_W[k];
    out[10] = 1.0f / (1.0f + expf(-acc));
  }
}

extern "C" void kernel_launch(void* const* d_in, const int* in_sizes, int n_in,
                              void* d_out, int out_size, void* d_ws, size_t ws_size,
                              hipStream_t stream) {
  const int N = NNODES;
  const float* xs[3] = {(const float*)d_in[0], (const float*)d_in[1], (const float*)d_in[2]};
  const int* eis[3] = {(const int*)d_in[3], (const int*)d_in[4], (const int*)d_in[5]};
  int Es[3];
  for (int s = 0; s < 3; s++) Es[s] = in_sizes[3 + s] / 2;

  const float* Wp[2]  = {(const float*)d_in[6],  (const float*)d_in[12]};
  const float* Bp[2]  = {(const float*)d_in[7],  (const float*)d_in[13]};
  const float* gp[2]  = {(const float*)d_in[8],  (const float*)d_in[14]};
  const float* btp[2] = {(const float*)d_in[9],  (const float*)d_in[15]};
  const float* mp[2]  = {(const float*)d_in[10], (const float*)d_in[16]};
  const float* vp[2]  = {(const float*)d_in[11], (const float*)d_in[17]};
  const float* W3p  = (const float*)d_in[18];
  const float* B3p  = (const float*)d_in[19];
  const float* g3p  = (const float*)d_in[20];
  const float* bt3p = (const float*)d_in[21];
  const float* m3p  = (const float*)d_in[22];
  const float* v3p  = (const float*)d_in[23];
  const float* fuse_W = (const float*)d_in[24];
  const float* fuse_b = (const float*)d_in[25];
  const float* cls_W  = (const float*)d_in[26];
  const float* cls_b  = (const float*)d_in[27];
  const float* reg_W  = (const float*)d_in[28];
  const float* reg_b  = (const float*)d_in[29];

  const int logKs[2] = {10, 8};
  const int douts[2] = {256, 128};

  size_t off = 0;
  auto alloc = [&](size_t nbytes) {
    char* p = (char*)d_ws + off;
    off += (nbytes + 255) & ~(size_t)255;
    return (void*)p;
  };
  int*   deg      = (int*)alloc(3 * (size_t)N * 4);
  float* dinv_all = (float*)alloc(3 * (size_t)N * 4);
  float* c_all    = (float*)alloc(3 * (size_t)N * 4);   // pool weights
  float* pooled   = (float*)alloc(3 * 128 * 4);
  int*   rowptr   = (int*)alloc((size_t)(N + 1) * 4);
  int*   cursor   = (int*)alloc((size_t)N * 4);
  int*   csr      = (int*)alloc((size_t)600000 * 4);
  unsigned short* Hbuf = (unsigned short*)alloc((size_t)N * 256 * 2);
  unsigned short* Xbf  = (unsigned short*)alloc((size_t)N * 256 * 2);
  unsigned short* Wt   = (unsigned short*)alloc((size_t)1024 * 256 * 2);
  (void)ws_size; (void)n_in; (void)out_size;

  hipMemsetAsync(deg, 0, 3 * (size_t)N * 4, stream);
  hipMemsetAsync(c_all, 0, 3 * (size_t)N * 4, stream);
  hipMemsetAsync(pooled, 0, 3 * 128 * 4, stream);

  for (int s = 0; s < 3; s++)
    deg_count_kernel<<<(Es[s] + 255) / 256, 256, 0, stream>>>(eis[s], Es[s], deg + (size_t)s * N);
  deg_finish_kernel<<<(3 * N + 255) / 256, 256, 0, stream>>>(deg, dinv_all, 3 * N);
  for (int s = 0; s < 3; s++)
    csum_count_kernel<<<(Es[s] + 255) / 256, 256, 0, stream>>>(eis[s], Es[s],
                                                               dinv_all + (size_t)s * N,
                                                               c_all + (size_t)s * N);
  c_finish_kernel<<<(3 * N + 255) / 256, 256, 0, stream>>>(dinv_all, c_all, 3 * N);

  const int MB = (N + 255) / 256;  // 196
  for (int s = 0; s < 3; s++) {
    const float* dinv = dinv_all + (size_t)s * N;
    scan_kernel<<<1, 1024, 0, stream>>>(deg + (size_t)s * N, rowptr, cursor, N);
    csr_fill_kernel<<<(Es[s] + 255) / 256, 256, 0, stream>>>(eis[s], Es[s], cursor, csr);

    for (int l = 0; l < 2; l++) {
      int logK = logKs[l], K = 1 << logK, C = douts[l];
      const float* W  = Wp[l]  + (size_t)s * K * C;
      const float* Bb = Bp[l]  + (size_t)s * C;
      const float* g  = gp[l]  + (size_t)s * C;
      const float* bt = btp[l] + (size_t)s * C;
      const float* m  = mp[l]  + (size_t)s * C;
      const float* v  = vp[l]  + (size_t)s * C;

      wt_kernel<<<(K * C + 255) / 256, 256, 0, stream>>>(W, Wt, logK, C);

      dim3 grid(C / 64, MB);
      if (l == 0)
        mfma_gemm_kernel<1><<<grid, 256, 0, stream>>>(xs[s], Wt, Hbuf, dinv, N, K, C);
      else
        mfma_gemm_kernel<0><<<grid, 256, 0, stream>>>(Xbf, Wt, Hbuf, dinv, N, K, C);

      if (l == 0)
        agg_kernel<4><<<(N + 3) / 4, 256, 0, stream>>>(Hbuf, rowptr, csr, dinv, Bb, g, bt, m, v,
                                                       Xbf, N);
      else
        agg_kernel<2><<<(N + 3) / 4, 256, 0, stream>>>(Hbuf, rowptr, csr, dinv, Bb, g, bt, m, v,
                                                       Xbf, N);
    }
    // layer 3 collapsed: pooled[s] = sum_j c[j] * X2[j]  (X2 = layer-2 output, C=128)
    colsum_kernel<<<512, 256, 0, stream>>>(Xbf, c_all + (size_t)s * N, pooled + s * 128, N);
  }

  head_kernel<<<1, 192, 0, stream>>>(pooled, W3p, B3p, g3p, bt3p, m3p, v3p, fuse_W, fuse_b,
                                     cls_W, cls_b, reg_W, reg_b, (float*)d_out);
}

// Round 6
// 847.515 us; speedup vs baseline: 8.2406x; 1.4425x over previous
//
#include <hip/hip_runtime.h>
#include <cstdint>
#include <cstddef>

#define NNODES 50000

typedef __attribute__((ext_vector_type(8))) short short8;
typedef __attribute__((ext_vector_type(4))) float f32x4;
typedef __attribute__((ext_vector_type(4))) unsigned short u16x4;
typedef __attribute__((ext_vector_type(2))) unsigned short u16x2;

__device__ __forceinline__ unsigned short f2bf(float f) {
  unsigned u = __builtin_bit_cast(unsigned, f);
  u = u + 0x7FFFu + ((u >> 16) & 1u);
  return (unsigned short)(u >> 16);
}
__device__ __forceinline__ float bf2f(unsigned short u) {
  return __builtin_bit_cast(float, (unsigned)u << 16);
}

// ---------------- degree (int counts) ----------------
__global__ void deg_count_kernel(const int* __restrict__ ei, int E, int* __restrict__ deg) {
  int i = blockIdx.x * blockDim.x + threadIdx.x;
  if (i < E) atomicAdd(&deg[ei[E + i]], 1);
}

__global__ void deg_finish_kernel(const int* __restrict__ deg, float* __restrict__ dinv, int n) {
  int i = blockIdx.x * blockDim.x + threadIdx.x;
  if (i < n) dinv[i] = rsqrtf((float)deg[i] + 1.0f);  // +1 self-loop
}

// ---------------- pool-weight c[j] = dinv[j]*(dinv[j] + sum_{edges src=j} dinv[dst]) --------
__global__ void csum_count_kernel(const int* __restrict__ ei, int E,
                                  const float* __restrict__ dinv, float* __restrict__ csum) {
  int i = blockIdx.x * blockDim.x + threadIdx.x;
  if (i < E) unsafeAtomicAdd(&csum[ei[i]], dinv[ei[E + i]]);
}

__global__ void c_finish_kernel(const float* __restrict__ dinv, float* __restrict__ csum, int n) {
  int i = blockIdx.x * blockDim.x + threadIdx.x;
  if (i < n) csum[i] = dinv[i] * (dinv[i] + csum[i]);
}

// ---------------- exclusive scan, one block per scale ----------------
__global__ void scan3_kernel(const int* __restrict__ deg, int* __restrict__ rowptr,
                             int* __restrict__ cursor, int n) {
  const int s = blockIdx.x;
  const int* dg = deg + (size_t)s * n;
  int* rp = rowptr + (size_t)s * (n + 1);
  int* cu = cursor + (size_t)s * n;
  __shared__ int tmp[1024];
  __shared__ int carry;
  const int tid = threadIdx.x;
  if (tid == 0) { carry = 0; rp[0] = 0; }
  __syncthreads();
  for (int base = 0; base < n; base += 1024) {
    int i = base + tid;
    int val = (i < n) ? dg[i] : 0;
    tmp[tid] = val;
    __syncthreads();
    for (int off = 1; off < 1024; off <<= 1) {
      int t = (tid >= off) ? tmp[tid - off] : 0;
      __syncthreads();
      tmp[tid] += t;
      __syncthreads();
    }
    int inc = tmp[tid] + carry;
    if (i < n) { rp[i + 1] = inc; cu[i] = inc - val; }
    __syncthreads();
    if (tid == 1023) carry = inc;
    __syncthreads();
  }
}

// ---------------- CSR fill ----------------
__global__ void csr_fill_kernel(const int* __restrict__ ei, int E, int* __restrict__ cursor,
                                int* __restrict__ csr) {
  int i = blockIdx.x * blockDim.x + threadIdx.x;
  if (i < E) {
    int src = ei[i];
    int dst = ei[E + i];
    int pos = atomicAdd(&cursor[dst], 1);
    if (pos < E) csr[pos] = src;
  }
}

// ---------------- batched weight transpose: all 3 scales, both layers ----------------
// l0: W[1024][256] -> Wt[n*1024+k] ; l1: W[256][128] -> Wt(+786432)[n*256+k]
__global__ void wt_all_kernel(const float* __restrict__ W0, const float* __restrict__ W1,
                              unsigned short* __restrict__ Wt) {
  int idx = blockIdx.x * blockDim.x + threadIdx.x;
  const int L0TOT = 3 * 262144;
  const int TOT = L0TOT + 3 * 32768;
  if (idx >= TOT) return;
  if (idx < L0TOT) {
    int s = idx / 262144, r = idx - s * 262144;
    int n = r >> 10, k = r & 1023;
    Wt[idx] = f2bf(W0[(size_t)s * 262144 + k * 256 + n]);
  } else {
    int j = idx - L0TOT;
    int s = j / 32768, r = j - s * 32768;
    int n = r >> 8, k = r & 255;
    Wt[idx] = f2bf(W1[(size_t)s * 32768 + k * 128 + n]);
  }
}

// ---------------- bf16 MFMA GEMM: BM=WR*64 rows/block, BN=WC*64=Nc (full width) ---------
// A fetched exactly once across the grid. 4 waves as WR x WC.
template <int A_FP32, int WR, int WC>
__global__ __launch_bounds__(256) void mfma_gemm_kernel(
    const void* __restrict__ Av, const unsigned short* __restrict__ Wt,
    unsigned short* __restrict__ H, const float* __restrict__ dinv, int M, int K, int Nc) {
  constexpr int BM = WR * 64;
  constexpr int BN = WC * 64;
  constexpr int AQ = BM * 64 / (256 * 8);
  constexpr int BQ = BN * 64 / (256 * 8);
  __shared__ unsigned short Alds[BM * 64];
  __shared__ unsigned short Blds[BN * 64];
  const int tid = threadIdx.x;
  const int lane = tid & 63;
  const int w = tid >> 6;
  const int wr = w / WC;
  const int wc = w - wr * WC;
  const int r0 = blockIdx.x * BM;
  const float* Af = (const float*)Av;
  const unsigned short* Ab = (const unsigned short*)Av;

  short8 aReg[AQ];
  short8 bReg[BQ];

  auto preload = [&](int k0) {
#pragma unroll
    for (int q = 0; q < AQ; q++) {
      int slot = q * 256 + tid;
      int row = slot >> 3;
      int s = slot & 7;
      int gr = r0 + row;
      if (gr > M - 1) gr = M - 1;  // clamp: never stored
      if (A_FP32) {
        const float* p = Af + (size_t)gr * K + k0 + s * 8;
        float4 u0 = *(const float4*)p;
        float4 u1 = *(const float4*)(p + 4);
        short8 t;
        t[0] = (short)f2bf(u0.x); t[1] = (short)f2bf(u0.y);
        t[2] = (short)f2bf(u0.z); t[3] = (short)f2bf(u0.w);
        t[4] = (short)f2bf(u1.x); t[5] = (short)f2bf(u1.y);
        t[6] = (short)f2bf(u1.z); t[7] = (short)f2bf(u1.w);
        aReg[q] = t;
      } else {
        aReg[q] = *(const short8*)(Ab + (size_t)gr * K + k0 + s * 8);
      }
    }
#pragma unroll
    for (int q = 0; q < BQ; q++) {
      int slot = q * 256 + tid;
      int n = slot >> 3;
      int s = slot & 7;
      bReg[q] = *(const short8*)(Wt + (size_t)n * K + k0 + s * 8);
    }
  };

  auto stage = [&]() {
#pragma unroll
    for (int q = 0; q < AQ; q++) {
      int slot = q * 256 + tid;
      int row = slot >> 3;
      int s = slot & 7;
      *(short8*)&Alds[row * 64 + (s ^ (row & 7)) * 8] = aReg[q];
    }
#pragma unroll
    for (int q = 0; q < BQ; q++) {
      int slot = q * 256 + tid;
      int n = slot >> 3;
      int s = slot & 7;
      *(short8*)&Blds[n * 64 + (s ^ (n & 7)) * 8] = bReg[q];
    }
  };

  f32x4 acc[4][4] = {};
  preload(0);
  for (int k0 = 0; k0 < K; k0 += 64) {
    __syncthreads();
    stage();
    __syncthreads();
    if (k0 + 64 < K) preload(k0 + 64);
#pragma unroll
    for (int kk = 0; kk < 2; kk++) {
      const int t16 = kk * 4 + (lane >> 4);
      short8 af[4], bfr[4];
#pragma unroll
      for (int mi = 0; mi < 4; mi++) {
        int row = wr * 64 + mi * 16 + (lane & 15);
        af[mi] = *(const short8*)&Alds[row * 64 + (t16 ^ (row & 7)) * 8];
      }
#pragma unroll
      for (int ni = 0; ni < 4; ni++) {
        int n = wc * 64 + ni * 16 + (lane & 15);
        bfr[ni] = *(const short8*)&Blds[n * 64 + (t16 ^ (n & 7)) * 8];
      }
#pragma unroll
      for (int mi = 0; mi < 4; mi++)
#pragma unroll
        for (int ni = 0; ni < 4; ni++)
          acc[mi][ni] =
              __builtin_amdgcn_mfma_f32_16x16x32_bf16(af[mi], bfr[ni], acc[mi][ni], 0, 0, 0);
    }
  }

  // C/D layout: col = lane&15, row = (lane>>4)*4 + reg
#pragma unroll
  for (int mi = 0; mi < 4; mi++) {
#pragma unroll
    for (int r = 0; r < 4; r++) {
      int gr = r0 + wr * 64 + mi * 16 + (lane >> 4) * 4 + r;
      if (gr < M) {
        float di = dinv[gr];
#pragma unroll
        for (int ni = 0; ni < 4; ni++) {
          int col = wc * 64 + ni * 16 + (lane & 15);
          H[(size_t)gr * Nc + col] = f2bf(acc[mi][ni][r] * di);
        }
      }
    }
  }
}

// ---------------- CSR gather + BN + ReLU -> bf16 ----------------
template <int VEC>
__device__ __forceinline__ void addrow(const unsigned short* __restrict__ p, float* acc) {
  if constexpr (VEC == 4) {
    u16x4 u = *(const u16x4*)p;
#pragma unroll
    for (int j = 0; j < 4; j++) acc[j] += bf2f(u[j]);
  } else {
    u16x2 u = *(const u16x2*)p;
    acc[0] += bf2f(u[0]);
    acc[1] += bf2f(u[1]);
  }
}

template <int VEC>
__global__ __launch_bounds__(256) void agg_kernel(
    const unsigned short* __restrict__ Hb, const int* __restrict__ rowptr,
    const int* __restrict__ csr, const float* __restrict__ dinv,
    const float* __restrict__ Bb, const float* __restrict__ g,
    const float* __restrict__ bt, const float* __restrict__ m,
    const float* __restrict__ v, unsigned short* __restrict__ X, int n) {
  const int C = VEC * 64;
  const int lane = threadIdx.x & 63;
  const int w = threadIdx.x >> 6;
  const int ch = lane * VEC;
  float a[VEC], sh[VEC];
#pragma unroll
  for (int j = 0; j < VEC; j++) {
    float aa = g[ch + j] * rsqrtf(v[ch + j] + 1e-5f);
    a[j] = aa;
    sh[j] = (Bb[ch + j] - m[ch + j]) * aa + bt[ch + j];
  }
  const int row = blockIdx.x * 4 + w;
  if (row >= n) return;
  float acc[VEC] = {};
  addrow<VEC>(Hb + (size_t)row * C + ch, acc);  // self
  int b0 = rowptr[row], b1 = rowptr[row + 1];
  int i = b0;
  for (; i + 4 <= b1; i += 4) {
    int s0 = csr[i], s1 = csr[i + 1], s2 = csr[i + 2], s3 = csr[i + 3];
    addrow<VEC>(Hb + (size_t)s0 * C + ch, acc);
    addrow<VEC>(Hb + (size_t)s1 * C + ch, acc);
    addrow<VEC>(Hb + (size_t)s2 * C + ch, acc);
    addrow<VEC>(Hb + (size_t)s3 * C + ch, acc);
  }
  for (; i < b1; i++) addrow<VEC>(Hb + (size_t)csr[i] * C + ch, acc);
  float dd = dinv[row];
  if constexpr (VEC == 4) {
    u16x4 o;
#pragma unroll
    for (int j = 0; j < 4; j++) o[j] = f2bf(fmaxf(acc[j] * dd * a[j] + sh[j], 0.0f));
    *(u16x4*)(X + (size_t)row * C + ch) = o;
  } else {
    u16x2 o;
    o[0] = f2bf(fmaxf(acc[0] * dd * a[0] + sh[0], 0.0f));
    o[1] = f2bf(fmaxf(acc[1] * dd * a[1] + sh[1], 0.0f));
    *(u16x2*)(X + (size_t)row * C + ch) = o;
  }
}

// ---------------- weighted column-sum: pooled[ch] = sum_j c[j] * X2[j][ch], C=128 -------
__global__ __launch_bounds__(256) void colsum_kernel(const unsigned short* __restrict__ X,
                                                     const float* __restrict__ c,
                                                     float* __restrict__ pooled, int n) {
  const int ch = threadIdx.x & 127;
  const int half = threadIdx.x >> 7;
  float acc = 0.0f;
  for (int row = blockIdx.x * 2 + half; row < n; row += gridDim.x * 2)
    acc += c[row] * bf2f(X[(size_t)row * 128 + ch]);
  __shared__ float red[256];
  red[threadIdx.x] = acc;
  __syncthreads();
  if (threadIdx.x < 128)
    unsafeAtomicAdd(&pooled[ch], red[threadIdx.x] + red[threadIdx.x + 128]);
}

// ---------------- head: per-scale BN3((pooled/N)@W3 + b3), fuse, cls, reg ----------------
__global__ void head_kernel(const float* __restrict__ pooled, const float* __restrict__ W3p,
                            const float* __restrict__ B3p, const float* __restrict__ g3p,
                            const float* __restrict__ bt3p, const float* __restrict__ m3p,
                            const float* __restrict__ v3p, const float* __restrict__ fuse_W,
                            const float* __restrict__ fuse_b, const float* __restrict__ cls_W,
                            const float* __restrict__ cls_b, const float* __restrict__ reg_W,
                            const float* __restrict__ reg_b, float* __restrict__ out) {
  __shared__ float e[192];
  __shared__ float fused[64];
  int t = threadIdx.x;
  if (t < 192) {
    int s = t >> 6, ch = t & 63;
    float acc = 0.0f;
    const float* W3 = W3p + (size_t)s * 128 * 64;
    const float* pv = pooled + s * 128;
    for (int k = 0; k < 128; k++) acc += pv[k] * W3[k * 64 + ch];
    float a3 = g3p[s * 64 + ch] * rsqrtf(v3p[s * 64 + ch] + 1e-5f);
    e[t] = (acc * (1.0f / (float)NNODES) + B3p[s * 64 + ch] - m3p[s * 64 + ch]) * a3 +
           bt3p[s * 64 + ch];
  }
  __syncthreads();
  if (t < 64) {
    float acc = fuse_b[t];
    for (int k = 0; k < 192; k++) acc += e[k] * fuse_W[k * 64 + t];
    fused[t] = fmaxf(acc, 0.0f);
  }
  __syncthreads();
  if (t < 10) {
    float acc = cls_b[t];
    for (int k = 0; k < 64; k++) acc += fused[k] * cls_W[k * 10 + t];
    out[t] = acc;
  }
  if (t == 64) {
    float acc = reg_b[0];
    for (int k = 0; k < 64; k++) acc += fused[k] * reg_W[k];
    out[10] = 1.0f / (1.0f + expf(-acc));
  }
}

extern "C" void kernel_launch(void* const* d_in, const int* in_sizes, int n_in,
                              void* d_out, int out_size, void* d_ws, size_t ws_size,
                              hipStream_t stream) {
  const int N = NNODES;
  const float* xs[3] = {(const float*)d_in[0], (const float*)d_in[1], (const float*)d_in[2]};
  const int* eis[3] = {(const int*)d_in[3], (const int*)d_in[4], (const int*)d_in[5]};
  int Es[3];
  for (int s = 0; s < 3; s++) Es[s] = in_sizes[3 + s] / 2;
  const int csrOff[3] = {0, Es[0], Es[0] + Es[1]};

  const float* Wp[2]  = {(const float*)d_in[6],  (const float*)d_in[12]};
  const float* Bp[2]  = {(const float*)d_in[7],  (const float*)d_in[13]};
  const float* gp[2]  = {(const float*)d_in[8],  (const float*)d_in[14]};
  const float* btp[2] = {(const float*)d_in[9],  (const float*)d_in[15]};
  const float* mp[2]  = {(const float*)d_in[10], (const float*)d_in[16]};
  const float* vp[2]  = {(const float*)d_in[11], (const float*)d_in[17]};
  const float* W3p  = (const float*)d_in[18];
  const float* B3p  = (const float*)d_in[19];
  const float* g3p  = (const float*)d_in[20];
  const float* bt3p = (const float*)d_in[21];
  const float* m3p  = (const float*)d_in[22];
  const float* v3p  = (const float*)d_in[23];
  const float* fuse_W = (const float*)d_in[24];
  const float* fuse_b = (const float*)d_in[25];
  const float* cls_W  = (const float*)d_in[26];
  const float* cls_b  = (const float*)d_in[27];
  const float* reg_W  = (const float*)d_in[28];
  const float* reg_b  = (const float*)d_in[29];

  size_t off = 0;
  auto alloc = [&](size_t nbytes) {
    char* p = (char*)d_ws + off;
    off += (nbytes + 255) & ~(size_t)255;
    return (void*)p;
  };
  int*   deg      = (int*)alloc(3 * (size_t)N * 4);
  float* dinv_all = (float*)alloc(3 * (size_t)N * 4);
  float* c_all    = (float*)alloc(3 * (size_t)N * 4);
  float* pooled   = (float*)alloc(3 * 128 * 4);
  int*   rowptr   = (int*)alloc(3 * (size_t)(N + 1) * 4);
  int*   cursor   = (int*)alloc(3 * (size_t)N * 4);
  int*   csr      = (int*)alloc((size_t)(Es[0] + Es[1] + Es[2]) * 4);
  unsigned short* Hbuf = (unsigned short*)alloc((size_t)N * 256 * 2);
  unsigned short* Xbf  = (unsigned short*)alloc((size_t)N * 256 * 2);
  unsigned short* Wt   = (unsigned short*)alloc((size_t)(3 * 262144 + 3 * 32768) * 2);
  (void)ws_size; (void)n_in; (void)out_size;

  hipMemsetAsync(deg, 0, 3 * (size_t)N * 4, stream);
  hipMemsetAsync(c_all, 0, 3 * (size_t)N * 4, stream);
  hipMemsetAsync(pooled, 0, 3 * 128 * 4, stream);

  // ---- graph prep (all scales, hoisted) ----
  for (int s = 0; s < 3; s++)
    deg_count_kernel<<<(Es[s] + 255) / 256, 256, 0, stream>>>(eis[s], Es[s], deg + (size_t)s * N);
  deg_finish_kernel<<<(3 * N + 255) / 256, 256, 0, stream>>>(deg, dinv_all, 3 * N);
  for (int s = 0; s < 3; s++)
    csum_count_kernel<<<(Es[s] + 255) / 256, 256, 0, stream>>>(eis[s], Es[s],
                                                               dinv_all + (size_t)s * N,
                                                               c_all + (size_t)s * N);
  c_finish_kernel<<<(3 * N + 255) / 256, 256, 0, stream>>>(dinv_all, c_all, 3 * N);
  scan3_kernel<<<3, 1024, 0, stream>>>(deg, rowptr, cursor, N);
  for (int s = 0; s < 3; s++)
    csr_fill_kernel<<<(Es[s] + 255) / 256, 256, 0, stream>>>(eis[s], Es[s],
                                                             cursor + (size_t)s * N,
                                                             csr + csrOff[s]);
  wt_all_kernel<<<(3 * 262144 + 3 * 32768 + 255) / 256, 256, 0, stream>>>(Wp[0], Wp[1], Wt);

  // ---- branches ----
  for (int s = 0; s < 3; s++) {
    const float* dinv = dinv_all + (size_t)s * N;
    const int* rp = rowptr + (size_t)s * (N + 1);
    const int* cs = csr + csrOff[s];

    // layer 0: K=1024, C=256
    {
      const unsigned short* Wts = Wt + (size_t)s * 262144;
      mfma_gemm_kernel<1, 1, 4><<<(N + 63) / 64, 256, 0, stream>>>(xs[s], Wts, Hbuf, dinv, N,
                                                                   1024, 256);
      agg_kernel<4><<<(N + 3) / 4, 256, 0, stream>>>(Hbuf, rp, cs, dinv,
                                                     Bp[0] + (size_t)s * 256,
                                                     gp[0] + (size_t)s * 256,
                                                     btp[0] + (size_t)s * 256,
                                                     mp[0] + (size_t)s * 256,
                                                     vp[0] + (size_t)s * 256, Xbf, N);
    }
    // layer 1: K=256, C=128
    {
      const unsigned short* Wts = Wt + (size_t)(3 * 262144) + (size_t)s * 32768;
      mfma_gemm_kernel<0, 2, 2><<<(N + 127) / 128, 256, 0, stream>>>(Xbf, Wts, Hbuf, dinv, N,
                                                                     256, 128);
      agg_kernel<2><<<(N + 3) / 4, 256, 0, stream>>>(Hbuf, rp, cs, dinv,
                                                     Bp[1] + (size_t)s * 128,
                                                     gp[1] + (size_t)s * 128,
                                                     btp[1] + (size_t)s * 128,
                                                     mp[1] + (size_t)s * 128,
                                                     vp[1] + (size_t)s * 128, Xbf, N);
    }
    // layer 3 collapsed: pooled[s] = sum_j c[j] * X2[j]
    colsum_kernel<<<512, 256, 0, stream>>>(Xbf, c_all + (size_t)s * N, pooled + s * 128, N);
  }

  head_kernel<<<1, 192, 0, stream>>>(pooled, W3p, B3p, g3p, bt3p, m3p, v3p, fuse_W, fuse_b,
                                     cls_W, cls_b, reg_W, reg_b, (float*)d_out);
}

// Round 7
// 736.823 us; speedup vs baseline: 9.4785x; 1.1502x over previous
//
#include <hip/hip_runtime.h>
#include <cstdint>
#include <cstddef>

#define NNODES 50000

typedef __attribute__((ext_vector_type(8))) short short8;
typedef __attribute__((ext_vector_type(4))) float f32x4;
typedef __attribute__((ext_vector_type(4))) unsigned short u16x4;
typedef __attribute__((ext_vector_type(2))) unsigned short u16x2;

__device__ __forceinline__ unsigned short f2bf(float f) {
  unsigned u = __builtin_bit_cast(unsigned, f);
  u = u + 0x7FFFu + ((u >> 16) & 1u);
  return (unsigned short)(u >> 16);
}
__device__ __forceinline__ float bf2f(unsigned short u) {
  return __builtin_bit_cast(float, (unsigned)u << 16);
}

// ---------------- batched degree count (grid.y = scale) ----------------
__global__ void deg_count3_kernel(const int* __restrict__ e0, const int* __restrict__ e1,
                                  const int* __restrict__ e2, int E0, int E1, int E2,
                                  int* __restrict__ deg, int n) {
  int s = blockIdx.y;
  const int* ei = s == 0 ? e0 : (s == 1 ? e1 : e2);
  int E = s == 0 ? E0 : (s == 1 ? E1 : E2);
  int i = blockIdx.x * blockDim.x + threadIdx.x;
  if (i < E) atomicAdd(&deg[(size_t)s * n + ei[E + i]], 1);
}

__global__ void deg_finish_kernel(const int* __restrict__ deg, float* __restrict__ dinv, int n) {
  int i = blockIdx.x * blockDim.x + threadIdx.x;
  if (i < n) dinv[i] = rsqrtf((float)deg[i] + 1.0f);  // +1 self-loop
}

// ---------------- batched pool-weight accumulate ----------------
__global__ void csum_count3_kernel(const int* __restrict__ e0, const int* __restrict__ e1,
                                   const int* __restrict__ e2, int E0, int E1, int E2,
                                   const float* __restrict__ dinv_all, float* __restrict__ csum,
                                   int n) {
  int s = blockIdx.y;
  const int* ei = s == 0 ? e0 : (s == 1 ? e1 : e2);
  int E = s == 0 ? E0 : (s == 1 ? E1 : E2);
  int i = blockIdx.x * blockDim.x + threadIdx.x;
  if (i < E)
    unsafeAtomicAdd(&csum[(size_t)s * n + ei[i]], dinv_all[(size_t)s * n + ei[E + i]]);
}

__global__ void c_finish_kernel(const float* __restrict__ dinv, float* __restrict__ csum, int n) {
  int i = blockIdx.x * blockDim.x + threadIdx.x;
  if (i < n) csum[i] = dinv[i] * (dinv[i] + csum[i]);
}

// ---------------- exclusive scan, one block per scale ----------------
__global__ void scan3_kernel(const int* __restrict__ deg, int* __restrict__ rowptr,
                             int* __restrict__ cursor, int n) {
  const int s = blockIdx.x;
  const int* dg = deg + (size_t)s * n;
  int* rp = rowptr + (size_t)s * (n + 1);
  int* cu = cursor + (size_t)s * n;
  __shared__ int tmp[1024];
  __shared__ int carry;
  const int tid = threadIdx.x;
  if (tid == 0) { carry = 0; rp[0] = 0; }
  __syncthreads();
  for (int base = 0; base < n; base += 1024) {
    int i = base + tid;
    int val = (i < n) ? dg[i] : 0;
    tmp[tid] = val;
    __syncthreads();
    for (int off = 1; off < 1024; off <<= 1) {
      int t = (tid >= off) ? tmp[tid - off] : 0;
      __syncthreads();
      tmp[tid] += t;
      __syncthreads();
    }
    int inc = tmp[tid] + carry;
    if (i < n) { rp[i + 1] = inc; cu[i] = inc - val; }
    __syncthreads();
    if (tid == 1023) carry = inc;
    __syncthreads();
  }
}

// ---------------- batched CSR fill ----------------
__global__ void csr_fill3_kernel(const int* __restrict__ e0, const int* __restrict__ e1,
                                 const int* __restrict__ e2, int E0, int E1, int E2,
                                 int* __restrict__ cursor, int* __restrict__ csr, int n) {
  int s = blockIdx.y;
  const int* ei = s == 0 ? e0 : (s == 1 ? e1 : e2);
  int E = s == 0 ? E0 : (s == 1 ? E1 : E2);
  int coff = (s > 0 ? E0 : 0) + (s > 1 ? E1 : 0);
  int i = blockIdx.x * blockDim.x + threadIdx.x;
  if (i < E) {
    int src = ei[i];
    int dst = ei[E + i];
    int pos = atomicAdd(&cursor[(size_t)s * n + dst], 1);
    csr[coff + pos] = src;
  }
}

// ---------------- batched weight transpose ----------------
__global__ void wt_all_kernel(const float* __restrict__ W0, const float* __restrict__ W1,
                              unsigned short* __restrict__ Wt) {
  int idx = blockIdx.x * blockDim.x + threadIdx.x;
  const int L0TOT = 3 * 262144;
  const int TOT = L0TOT + 3 * 32768;
  if (idx >= TOT) return;
  if (idx < L0TOT) {
    int s = idx / 262144, r = idx - s * 262144;
    int n = r >> 10, k = r & 1023;
    Wt[idx] = f2bf(W0[(size_t)s * 262144 + k * 256 + n]);
  } else {
    int j = idx - L0TOT;
    int s = j / 32768, r = j - s * 32768;
    int n = r >> 8, k = r & 255;
    Wt[idx] = f2bf(W1[(size_t)s * 32768 + k * 128 + n]);
  }
}

// ---------------- bf16 MFMA GEMM, all 3 scales (grid.y), 2-deep A prefetch ----------------
// A: [M][K] per scale (fp32 if A_FP32 else bf16); Wt: [Nc][K] bf16 per scale.
// Epilogue: H'[r][c] = (A@W)[r][c] * dinv[r], stored bf16.
template <int A_FP32, int WR, int WC>
__global__ __launch_bounds__(256) void mfma_gemm3_kernel(
    const void* __restrict__ A0v, const void* __restrict__ A1v, const void* __restrict__ A2v,
    const unsigned short* __restrict__ Wt, int wtStride,
    unsigned short* __restrict__ H, size_t hStride,
    const float* __restrict__ dinv_all, int M, int K, int Nc) {
  constexpr int BM = WR * 64;
  constexpr int BN = WC * 64;
  constexpr int AQ = BM * 64 / (256 * 8);
  constexpr int BQ = BN * 64 / (256 * 8);
  __shared__ unsigned short Alds[BM * 64];
  __shared__ unsigned short Blds[BN * 64];
  const int sc = blockIdx.y;
  const void* Av = sc == 0 ? A0v : (sc == 1 ? A1v : A2v);
  const unsigned short* Wts = Wt + (size_t)sc * wtStride;
  unsigned short* Hs = H + (size_t)sc * hStride;
  const float* dinv = dinv_all + (size_t)sc * M;
  const int tid = threadIdx.x;
  const int lane = tid & 63;
  const int w = tid >> 6;
  const int wr = w / WC;
  const int wc = w - wr * WC;
  const int r0 = blockIdx.x * BM;
  const float* Af = (const float*)Av;
  const unsigned short* Ab = (const unsigned short*)Av;

  short8 aR0[AQ], aR1[AQ], bR[BQ];

  auto preloadA = [&](int k0, short8 (&aR)[AQ]) {
#pragma unroll
    for (int q = 0; q < AQ; q++) {
      int slot = q * 256 + tid;
      int row = slot >> 3;
      int s = slot & 7;
      int gr = r0 + row;
      if (gr > M - 1) gr = M - 1;  // clamp: never stored
      if (A_FP32) {
        const float* p = Af + (size_t)gr * K + k0 + s * 8;
        float4 u0 = *(const float4*)p;
        float4 u1 = *(const float4*)(p + 4);
        short8 t;
        t[0] = (short)f2bf(u0.x); t[1] = (short)f2bf(u0.y);
        t[2] = (short)f2bf(u0.z); t[3] = (short)f2bf(u0.w);
        t[4] = (short)f2bf(u1.x); t[5] = (short)f2bf(u1.y);
        t[6] = (short)f2bf(u1.z); t[7] = (short)f2bf(u1.w);
        aR[q] = t;
      } else {
        aR[q] = *(const short8*)(Ab + (size_t)gr * K + k0 + s * 8);
      }
    }
  };

  auto preloadB = [&](int k0) {
#pragma unroll
    for (int q = 0; q < BQ; q++) {
      int slot = q * 256 + tid;
      int n = slot >> 3;
      int s = slot & 7;
      bR[q] = *(const short8*)(Wts + (size_t)n * K + k0 + s * 8);
    }
  };

  auto stage = [&](short8 (&aR)[AQ]) {
#pragma unroll
    for (int q = 0; q < AQ; q++) {
      int slot = q * 256 + tid;
      int row = slot >> 3;
      int s = slot & 7;
      *(short8*)&Alds[row * 64 + (s ^ (row & 7)) * 8] = aR[q];
    }
#pragma unroll
    for (int q = 0; q < BQ; q++) {
      int slot = q * 256 + tid;
      int n = slot >> 3;
      int s = slot & 7;
      *(short8*)&Blds[n * 64 + (s ^ (n & 7)) * 8] = bR[q];
    }
  };

  f32x4 acc[4][4] = {};

  auto compute = [&]() {
#pragma unroll
    for (int kk = 0; kk < 2; kk++) {
      const int t16 = kk * 4 + (lane >> 4);
      short8 af[4], bfr[4];
#pragma unroll
      for (int mi = 0; mi < 4; mi++) {
        int row = wr * 64 + mi * 16 + (lane & 15);
        af[mi] = *(const short8*)&Alds[row * 64 + (t16 ^ (row & 7)) * 8];
      }
#pragma unroll
      for (int ni = 0; ni < 4; ni++) {
        int n = wc * 64 + ni * 16 + (lane & 15);
        bfr[ni] = *(const short8*)&Blds[n * 64 + (t16 ^ (n & 7)) * 8];
      }
#pragma unroll
      for (int mi = 0; mi < 4; mi++)
#pragma unroll
        for (int ni = 0; ni < 4; ni++)
          acc[mi][ni] =
              __builtin_amdgcn_mfma_f32_16x16x32_bf16(af[mi], bfr[ni], acc[mi][ni], 0, 0, 0);
    }
  };

  // prologue: 2 A-tiles + 1 B-tile in flight
  preloadA(0, aR0);
  preloadA(64, aR1);
  preloadB(0);
  for (int k0 = 0; k0 < K; k0 += 128) {
    // sub-step 0: consume (k0, set0)
    __syncthreads();
    stage(aR0);
    __syncthreads();
    preloadB(k0 + 64);
    if (k0 + 128 < K) preloadA(k0 + 128, aR0);
    compute();
    // sub-step 1: consume (k0+64, set1)
    __syncthreads();
    stage(aR1);
    __syncthreads();
    if (k0 + 128 < K) preloadB(k0 + 128);
    if (k0 + 192 < K) preloadA(k0 + 192, aR1);
    compute();
  }

  // C/D layout: col = lane&15, row = (lane>>4)*4 + reg
#pragma unroll
  for (int mi = 0; mi < 4; mi++) {
#pragma unroll
    for (int r = 0; r < 4; r++) {
      int gr = r0 + wr * 64 + mi * 16 + (lane >> 4) * 4 + r;
      if (gr < M) {
        float di = dinv[gr];
#pragma unroll
        for (int ni = 0; ni < 4; ni++) {
          int col = wc * 64 + ni * 16 + (lane & 15);
          Hs[(size_t)gr * Nc + col] = f2bf(acc[mi][ni][r] * di);
        }
      }
    }
  }
}

// ---------------- batched CSR gather + BN + ReLU -> bf16 (grid.y = scale) ----------------
template <int VEC>
__device__ __forceinline__ void addrow(const unsigned short* __restrict__ p, float* acc) {
  if constexpr (VEC == 4) {
    u16x4 u = *(const u16x4*)p;
#pragma unroll
    for (int j = 0; j < 4; j++) acc[j] += bf2f(u[j]);
  } else {
    u16x2 u = *(const u16x2*)p;
    acc[0] += bf2f(u[0]);
    acc[1] += bf2f(u[1]);
  }
}

template <int VEC>
__global__ __launch_bounds__(256) void agg3_kernel(
    const unsigned short* __restrict__ Hb, size_t hStride,
    const int* __restrict__ rowptr, const int* __restrict__ csr, int E0, int E1,
    const float* __restrict__ dinv_all,
    const float* __restrict__ Bb, const float* __restrict__ g,
    const float* __restrict__ bt, const float* __restrict__ m,
    const float* __restrict__ v, unsigned short* __restrict__ X, size_t xStride, int n) {
  const int C = VEC * 64;
  const int sIdx = blockIdx.y;
  const unsigned short* Hs = Hb + (size_t)sIdx * hStride;
  unsigned short* Xs = X + (size_t)sIdx * xStride;
  const int* rp = rowptr + (size_t)sIdx * (n + 1);
  const int* cs = csr + (sIdx > 0 ? E0 : 0) + (sIdx > 1 ? E1 : 0);
  const float* dinv = dinv_all + (size_t)sIdx * n;
  const int lane = threadIdx.x & 63;
  const int w = threadIdx.x >> 6;
  const int ch = lane * VEC;
  float a[VEC], sh[VEC];
#pragma unroll
  for (int j = 0; j < VEC; j++) {
    float aa = g[sIdx * C + ch + j] * rsqrtf(v[sIdx * C + ch + j] + 1e-5f);
    a[j] = aa;
    sh[j] = (Bb[sIdx * C + ch + j] - m[sIdx * C + ch + j]) * aa + bt[sIdx * C + ch + j];
  }
  const int row = blockIdx.x * 4 + w;
  if (row >= n) return;
  float acc[VEC] = {};
  addrow<VEC>(Hs + (size_t)row * C + ch, acc);  // self
  int b0 = rp[row], b1 = rp[row + 1];
  int i = b0;
  for (; i + 4 <= b1; i += 4) {
    int s0 = cs[i], s1 = cs[i + 1], s2 = cs[i + 2], s3 = cs[i + 3];
    addrow<VEC>(Hs + (size_t)s0 * C + ch, acc);
    addrow<VEC>(Hs + (size_t)s1 * C + ch, acc);
    addrow<VEC>(Hs + (size_t)s2 * C + ch, acc);
    addrow<VEC>(Hs + (size_t)s3 * C + ch, acc);
  }
  for (; i < b1; i++) addrow<VEC>(Hs + (size_t)cs[i] * C + ch, acc);
  float dd = dinv[row];
  if constexpr (VEC == 4) {
    u16x4 o;
#pragma unroll
    for (int j = 0; j < 4; j++) o[j] = f2bf(fmaxf(acc[j] * dd * a[j] + sh[j], 0.0f));
    *(u16x4*)(Xs + (size_t)row * C + ch) = o;
  } else {
    u16x2 o;
    o[0] = f2bf(fmaxf(acc[0] * dd * a[0] + sh[0], 0.0f));
    o[1] = f2bf(fmaxf(acc[1] * dd * a[1] + sh[1], 0.0f));
    *(u16x2*)(Xs + (size_t)row * C + ch) = o;
  }
}

// ---------------- batched weighted column-sum (C=128) ----------------
__global__ __launch_bounds__(256) void colsum3_kernel(const unsigned short* __restrict__ X,
                                                      size_t xStride,
                                                      const float* __restrict__ c_all,
                                                      float* __restrict__ pooled, int n) {
  const int s = blockIdx.y;
  const unsigned short* Xs = X + (size_t)s * xStride;
  const float* c = c_all + (size_t)s * n;
  const int ch = threadIdx.x & 127;
  const int half = threadIdx.x >> 7;
  float acc = 0.0f;
  for (int row = blockIdx.x * 2 + half; row < n; row += gridDim.x * 2)
    acc += c[row] * bf2f(Xs[(size_t)row * 128 + ch]);
  __shared__ float red[256];
  red[threadIdx.x] = acc;
  __syncthreads();
  if (threadIdx.x < 128)
    unsafeAtomicAdd(&pooled[s * 128 + ch], red[threadIdx.x] + red[threadIdx.x + 128]);
}

// ---------------- head: per-scale BN3((pooled/N)@W3 + b3), fuse, cls, reg ----------------
__global__ void head_kernel(const float* __restrict__ pooled, const float* __restrict__ W3p,
                            const float* __restrict__ B3p, const float* __restrict__ g3p,
                            const float* __restrict__ bt3p, const float* __restrict__ m3p,
                            const float* __restrict__ v3p, const float* __restrict__ fuse_W,
                            const float* __restrict__ fuse_b, const float* __restrict__ cls_W,
                            const float* __restrict__ cls_b, const float* __restrict__ reg_W,
                            const float* __restrict__ reg_b, float* __restrict__ out) {
  __shared__ float e[192];
  __shared__ float fused[64];
  int t = threadIdx.x;
  if (t < 192) {
    int s = t >> 6, ch = t & 63;
    float acc = 0.0f;
    const float* W3 = W3p + (size_t)s * 128 * 64;
    const float* pv = pooled + s * 128;
    for (int k = 0; k < 128; k++) acc += pv[k] * W3[k * 64 + ch];
    float a3 = g3p[s * 64 + ch] * rsqrtf(v3p[s * 64 + ch] + 1e-5f);
    e[t] = (acc * (1.0f / (float)NNODES) + B3p[s * 64 + ch] - m3p[s * 64 + ch]) * a3 +
           bt3p[s * 64 + ch];
  }
  __syncthreads();
  if (t < 64) {
    float acc = fuse_b[t];
    for (int k = 0; k < 192; k++) acc += e[k] * fuse_W[k * 64 + t];
    fused[t] = fmaxf(acc, 0.0f);
  }
  __syncthreads();
  if (t < 10) {
    float acc = cls_b[t];
    for (int k = 0; k < 64; k++) acc += fused[k] * cls_W[k * 10 + t];
    out[t] = acc;
  }
  if (t == 64) {
    float acc = reg_b[0];
    for (int k = 0; k < 64; k++) acc += fused[k] * reg_W[k];
    out[10] = 1.0f / (1.0f + expf(-acc));
  }
}

extern "C" void kernel_launch(void* const* d_in, const int* in_sizes, int n_in,
                              void* d_out, int out_size, void* d_ws, size_t ws_size,
                              hipStream_t stream) {
  const int N = NNODES;
  const float* xs[3] = {(const float*)d_in[0], (const float*)d_in[1], (const float*)d_in[2]};
  const int* eis[3] = {(const int*)d_in[3], (const int*)d_in[4], (const int*)d_in[5]};
  int Es[3];
  for (int s = 0; s < 3; s++) Es[s] = in_sizes[3 + s] / 2;
  int maxE = Es[0] > Es[1] ? Es[0] : Es[1];
  if (Es[2] > maxE) maxE = Es[2];

  const float* Wp[2]  = {(const float*)d_in[6],  (const float*)d_in[12]};
  const float* Bp[2]  = {(const float*)d_in[7],  (const float*)d_in[13]};
  const float* gp[2]  = {(const float*)d_in[8],  (const float*)d_in[14]};
  const float* btp[2] = {(const float*)d_in[9],  (const float*)d_in[15]};
  const float* mp[2]  = {(const float*)d_in[10], (const float*)d_in[16]};
  const float* vp[2]  = {(const float*)d_in[11], (const float*)d_in[17]};
  const float* W3p  = (const float*)d_in[18];
  const float* B3p  = (const float*)d_in[19];
  const float* g3p  = (const float*)d_in[20];
  const float* bt3p = (const float*)d_in[21];
  const float* m3p  = (const float*)d_in[22];
  const float* v3p  = (const float*)d_in[23];
  const float* fuse_W = (const float*)d_in[24];
  const float* fuse_b = (const float*)d_in[25];
  const float* cls_W  = (const float*)d_in[26];
  const float* cls_b  = (const float*)d_in[27];
  const float* reg_W  = (const float*)d_in[28];
  const float* reg_b  = (const float*)d_in[29];

  size_t off = 0;
  auto alloc = [&](size_t nbytes) {
    char* p = (char*)d_ws + off;
    off += (nbytes + 255) & ~(size_t)255;
    return (void*)p;
  };
  int*   deg      = (int*)alloc(3 * (size_t)N * 4);
  float* dinv_all = (float*)alloc(3 * (size_t)N * 4);
  float* c_all    = (float*)alloc(3 * (size_t)N * 4);
  float* pooled   = (float*)alloc(3 * 128 * 4);
  int*   rowptr   = (int*)alloc(3 * (size_t)(N + 1) * 4);
  int*   cursor   = (int*)alloc(3 * (size_t)N * 4);
  int*   csr      = (int*)alloc((size_t)(Es[0] + Es[1] + Es[2]) * 4);
  unsigned short* Hbuf = (unsigned short*)alloc(3 * (size_t)N * 256 * 2);  // 76.8 MB
  unsigned short* Xbf  = (unsigned short*)alloc(3 * (size_t)N * 256 * 2);  // 76.8 MB
  unsigned short* Wt   = (unsigned short*)alloc((size_t)(3 * 262144 + 3 * 32768) * 2);
  (void)ws_size; (void)n_in; (void)out_size;

  const size_t HS = (size_t)N * 256;  // per-scale stride for Hbuf/Xbf (elements)

  hipMemsetAsync(deg, 0, 3 * (size_t)N * 4, stream);
  hipMemsetAsync(c_all, 0, 3 * (size_t)N * 4, stream);
  hipMemsetAsync(pooled, 0, 3 * 128 * 4, stream);

  // ---- graph prep (all scales batched) ----
  dim3 eg((maxE + 255) / 256, 3);
  deg_count3_kernel<<<eg, 256, 0, stream>>>(eis[0], eis[1], eis[2], Es[0], Es[1], Es[2], deg, N);
  deg_finish_kernel<<<(3 * N + 255) / 256, 256, 0, stream>>>(deg, dinv_all, 3 * N);
  csum_count3_kernel<<<eg, 256, 0, stream>>>(eis[0], eis[1], eis[2], Es[0], Es[1], Es[2],
                                             dinv_all, c_all, N);
  c_finish_kernel<<<(3 * N + 255) / 256, 256, 0, stream>>>(dinv_all, c_all, 3 * N);
  scan3_kernel<<<3, 1024, 0, stream>>>(deg, rowptr, cursor, N);
  csr_fill3_kernel<<<eg, 256, 0, stream>>>(eis[0], eis[1], eis[2], Es[0], Es[1], Es[2], cursor,
                                           csr, N);
  wt_all_kernel<<<(3 * 262144 + 3 * 32768 + 255) / 256, 256, 0, stream>>>(Wp[0], Wp[1], Wt);

  // ---- layer 0: K=1024, C=256, all scales in one dispatch ----
  mfma_gemm3_kernel<1, 1, 4><<<dim3((N + 63) / 64, 3), 256, 0, stream>>>(
      xs[0], xs[1], xs[2], Wt, 262144, Hbuf, HS, dinv_all, N, 1024, 256);
  agg3_kernel<4><<<dim3((N + 3) / 4, 3), 256, 0, stream>>>(
      Hbuf, HS, rowptr, csr, Es[0], Es[1], dinv_all, Bp[0], gp[0], btp[0], mp[0], vp[0], Xbf,
      HS, N);

  // ---- layer 1: K=256, C=128, all scales in one dispatch ----
  mfma_gemm3_kernel<0, 2, 2><<<dim3((N + 127) / 128, 3), 256, 0, stream>>>(
      Xbf, Xbf + HS, Xbf + 2 * HS, Wt + 3 * 262144, 32768, Hbuf, HS, dinv_all, N, 256, 128);
  agg3_kernel<2><<<dim3((N + 3) / 4, 3), 256, 0, stream>>>(
      Hbuf, HS, rowptr, csr, Es[0], Es[1], dinv_all, Bp[1], gp[1], btp[1], mp[1], vp[1], Xbf,
      HS, N);

  // ---- layer 3 collapsed: pooled[s] = sum_j c[j] * X2[j] ----
  colsum3_kernel<<<dim3(512, 3), 256, 0, stream>>>(Xbf, HS, c_all, pooled, N);

  head_kernel<<<1, 192, 0, stream>>>(pooled, W3p, B3p, g3p, bt3p, m3p, v3p, fuse_W, fuse_b,
                                     cls_W, cls_b, reg_W, reg_b, (float*)d_out);
}